// Round 15
// baseline (234.942 us; speedup 1.0000x reference)
//
#include <hip/hip_runtime.h>
#include <hip/hip_bf16.h>

#define B_   4
#define IC   64
#define OC   128
#define HH   128
#define WW   128
#define HP   130      // padded H/W for sampling
#define XOF  384      // x_off spatial (128*3)
#define XPAD 388      // padded x-dim of granule layout
#define OH2  382      // final output spatial

typedef __attribute__((ext_vector_type(4))) float f32x4;
typedef __attribute__((ext_vector_type(8))) __bf16 bf16x8;
typedef __attribute__((ext_vector_type(8))) unsigned short us8;
typedef __attribute__((ext_vector_type(4), aligned(4))) float f32x4u;

__device__ __forceinline__ float bf2f(unsigned short u) {
    union { unsigned int i; float f; } v; v.i = ((unsigned int)u) << 16; return v.f;
}
__device__ __forceinline__ unsigned short f2bf(float f) {
    __hip_bfloat16 h = __float2bfloat16(f);
    return reinterpret_cast<unsigned short&>(h);
}

// ---------------------------------------------------------------------------
// FUSED PROLOGUE (byte-identical to R14): transpose-to-bf16-NHWC / offset
// conv / prep_w in one dispatch.
// ---------------------------------------------------------------------------
__global__ __launch_bounds__(256) void prologue(const float* __restrict__ x,
                                                const float* __restrict__ w_p,
                                                const float* __restrict__ b_p,
                                                const float* __restrict__ wc,
                                                float* __restrict__ off,
                                                unsigned short* __restrict__ xt,
                                                unsigned short* __restrict__ Bt) {
    __shared__ __align__(16) char smem[18432];
    int bid = blockIdx.x;
    int tid = threadIdx.x;

    if (bid < 2048) {
        // ---- transpose to bf16 NHWC ----
        unsigned short (*tile)[34] = (unsigned short(*)[34])smem;  // 64x34 ushort
        int xt4 = bid & 3;
        int y   = (bid >> 2) & 127;
        int b   = bid >> 9;
        int x0  = xt4 * 32;

        int xl = tid & 31;
        int c8 = tid >> 5;
#pragma unroll
        for (int it = 0; it < 8; ++it) {
            int c = it * 8 + c8;
            tile[c][xl] = f2bf(x[(((size_t)b * IC + c) * HH + y) * WW + x0 + xl]);
        }
        __syncthreads();
        int c2 = (tid & 31) * 2;
#pragma unroll
        for (int it = 0; it < 4; ++it) {
            int xx = (tid >> 5) + it * 8;
            ushort2 v = { tile[c2][xx], tile[c2 + 1][xx] };
            *(ushort2*)(xt + (((size_t)b * HH + y) * WW + x0 + xx) * IC + c2) = v;
        }
    } else if (bid < 3072) {
        // ---- offset conv ----
        float (*part)[64][18] = (float(*)[64][18])smem;   // 4x64x18 f32
        int obid = bid - 2048;
        int pxl = tid & 63;
        int icq = tid >> 6;
        int seg = obid & 1;
        int row = obid >> 1;
        int py  = row & 127;
        int b   = row >> 7;
        int px  = seg * 64 + pxl;
        int ic0 = __builtin_amdgcn_readfirstlane(icq << 4);

        float acc[18];
#pragma unroll
        for (int co = 0; co < 18; ++co) acc[co] = 0.f;

        const float* xb = x + ((size_t)b * IC + ic0) * HH * WW;

        for (int ci = 0; ci < 16; ++ci) {
            const float* xc = xb + (size_t)ci * HH * WW;
            float xv[9];
#pragma unroll
            for (int ky = 0; ky < 3; ++ky) {
                int yy = py + ky - 1;
                bool yok = (yy >= 0) && (yy < HH);
#pragma unroll
                for (int kx = 0; kx < 3; ++kx) {
                    int xx = px + kx - 1;
                    bool ok = yok && (xx >= 0) && (xx < WW);
                    xv[ky * 3 + kx] = ok ? xc[yy * WW + xx] : 0.f;
                }
            }
#pragma unroll
            for (int co = 0; co < 18; ++co) {
                const float* wrow = w_p + ((size_t)co * IC + ic0 + ci) * 9;
                f32x4u w0 = *(const f32x4u*)wrow;
                f32x4u w1 = *(const f32x4u*)(wrow + 4);
                float  w8 = wrow[8];
                acc[co] = fmaf(w0.x, xv[0], acc[co]);
                acc[co] = fmaf(w0.y, xv[1], acc[co]);
                acc[co] = fmaf(w0.z, xv[2], acc[co]);
                acc[co] = fmaf(w0.w, xv[3], acc[co]);
                acc[co] = fmaf(w1.x, xv[4], acc[co]);
                acc[co] = fmaf(w1.y, xv[5], acc[co]);
                acc[co] = fmaf(w1.z, xv[6], acc[co]);
                acc[co] = fmaf(w1.w, xv[7], acc[co]);
                acc[co] = fmaf(w8,   xv[8], acc[co]);
            }
        }

#pragma unroll
        for (int co = 0; co < 18; ++co) part[icq][pxl][co] = acc[co];
        __syncthreads();

        for (int co = icq; co < 18; co += 4) {
            float s = b_p[co] + part[0][pxl][co] + part[1][pxl][co]
                              + part[2][pxl][co] + part[3][pxl][co];
            off[((size_t)b * 18 + co) * HH * WW + (size_t)py * WW + px] = s;
        }
    } else {
        // ---- prep_w ----
        int t = (bid - 3072) * 256 + tid;
        if (t < 18 * 4 * 128 * 8) {
            int e  = t & 7;
            int oc = (t >> 3) & 127;
            int kg = (t >> 10) & 3;
            int s  = t >> 12;
            int ic = ((s & 1) << 5) + (kg << 3) + e;
            int kpos = s >> 1;
            int ky = kpos / 3, kx = kpos % 3;
            Bt[t] = f2bf(wc[(((size_t)oc * IC + ic) * 3 + ky) * 3 + kx]);
        }
    }
}

// ---------------------------------------------------------------------------
// Kernel B v4 (byte-identical to R14): bilinear sampling from bf16 NHWC xt.
// ---------------------------------------------------------------------------
__global__ __launch_bounds__(256) void sample_nhwc(const unsigned short* __restrict__ xt,
                                                   const float* __restrict__ off,
                                                   unsigned short* __restrict__ xoff,
                                                   int b0, int nwg) {
    int orig = blockIdx.x;
    int chunk = nwg >> 3;
    int wg = (orig & 7) * chunk + (orig >> 3);

    int xtile = wg % 12;
    int tmp = wg / 12;
    int yy  = tmp % XOF;
    int bl  = tmp / XOF;
    int b   = b0 + bl;
    int xx0 = xtile * 32;

    int t  = threadIdx.x;
    int xl = t & 31;
    int cg = t >> 5;
    int xx = xx0 + xl;

    int j = xx / 3, kw = xx % 3;
    int i = yy / 3, kh = yy % 3;
    int n = kh * 3 + kw;

    const float* offb = off + (size_t)b * 18 * HH * WW + (size_t)i * WW + j;
    float offr = offb[(size_t)n * HH * WW];
    float offc = offb[(size_t)(n + 9) * HH * WW];

    float pr = (float)(i + kh) + offr;
    float pc = (float)(j + kw) + offc;

    float r0f = floorf(pr), c0f = floorf(pc);
    int r0 = min(max((int)r0f, 0), HP - 1);
    int c0 = min(max((int)c0f, 0), HP - 1);
    int r1 = min(max((int)(r0f + 1.f), 0), HP - 1);
    int c1 = min(max((int)(c0f + 1.f), 0), HP - 1);

    float prc = fminf(fmaxf(pr, 0.f), (float)(HP - 1));
    float pcc = fminf(fmaxf(pc, 0.f), (float)(HP - 1));

    float R0 = 1.f + ((float)r0 - prc);
    float R1 = 1.f - ((float)r1 - prc);
    float C0 = 1.f + ((float)c0 - pcc);
    float C1 = 1.f - ((float)c1 - pcc);

    int rr0 = r0 - 1, cc0 = c0 - 1, rr1 = r1 - 1, cc1 = c1 - 1;
    if (!(rr0 >= 0 && rr0 < HH)) R0 = 0.f;
    if (!(rr1 >= 0 && rr1 < HH)) R1 = 0.f;
    float C0m = (cc0 >= 0 && cc0 < WW) ? C0 : 0.f;
    float C1m = (cc1 >= 0 && cc1 < WW) ? C1 : 0.f;
    int ra0 = min(max(rr0, 0), HH - 1);
    int ra1 = min(max(rr1, 0), HH - 1);
    int ca0 = min(max(cc0, 0), WW - 1);
    int ca1 = min(max(cc1, 0), WW - 1);

    const unsigned short* xb = xt + (size_t)b * HH * WW * IC + cg * 8;
    us8 a  = *(const us8*)(xb + ((size_t)ra0 * WW + ca0) * IC);
    us8 bb = *(const us8*)(xb + ((size_t)ra0 * WW + ca1) * IC);
    us8 cc = *(const us8*)(xb + ((size_t)ra1 * WW + ca0) * IC);
    us8 dd = *(const us8*)(xb + ((size_t)ra1 * WW + ca1) * IC);

    us8 res;
#pragma unroll
    for (int e = 0; e < 8; ++e) {
        float v = R0 * (C0m * bf2f(a[e]) + C1m * bf2f(bb[e])) +
                  R1 * (C0m * bf2f(cc[e]) + C1m * bf2f(dd[e]));
        res[e] = f2bf(v);
    }

    size_t di = ((((size_t)bl * XOF + yy) * 8 + cg) * XPAD + xx) * 8;
    *(us8*)(xoff + di) = res;
}

// ---------------------------------------------------------------------------
// Kernel C v9: register-direct bf16 MFMA implicit-GEMM conv.
// NO LDS, NO BARRIERS. A and B fragments loaded global->VGPR (A: 4 coalesced
// dwordx4 off a per-lane voffset; B: L2-resident 144KB table). Fully unrolled
// 18 K-steps, ping-pong fragment sets, 1-step prefetch: the compiler emits
// counted vmcnt waits for register-dependent loads (the async-pipeline
// semantics that global_load_lds + barrier forbids). Waves fully self-paced.
// ---------------------------------------------------------------------------
__global__ __launch_bounds__(256) void conv2_mfma(const unsigned short* __restrict__ xoff,
                                                  const unsigned short* __restrict__ Bt,
                                                  float* __restrict__ out,
                                                  int b0, int nwg) {
    // bijective XCD-chunk swizzle (m204)
    int orig = blockIdx.x;
    int q = nwg >> 3, r = nwg & 7;
    int xcd = orig & 7, loc = orig >> 3;
    int wgid = (xcd < r ? xcd * (q + 1) : r * (q + 1) + (xcd - r) * q) + loc;

    int xt  = wgid % 3;
    int tmp = wgid / 3;
    int oy  = tmp % OH2;
    int bl  = tmp / OH2;
    int x0  = xt << 7;

    int tid  = threadIdx.x;
    int wave = tid >> 6, lane = tid & 63;
    int wm = wave >> 1;            // px half
    int wn = wave & 1;             // oc half
    int lr = lane & 15, lc = lane >> 4;

    const char* xb = (const char*)xoff + (size_t)bl * ((size_t)XOF * 8 * XPAD * 16);
    const char* baseA = xb + ((size_t)oy * 8 * XPAD + x0) * 16;
    const char* bt = (const char*)Bt;

    // per-lane voffsets (fragment addresses are affine in lane)
    const int voffA = (lc * XPAD + wm * 64 + lr) * 16;
    const int voffB = (lc * 128 + wn * 64 + lr) * 16;

    f32x4 acc[4][4];
#pragma unroll
    for (int mf = 0; mf < 4; ++mf)
#pragma unroll
        for (int nf = 0; nf < 4; ++nf)
            acc[mf][nf] = (f32x4){0.f, 0.f, 0.f, 0.f};

    auto loadA = [&](bf16x8* af, int t) {
        const int ky = t / 6, ich = (t / 3) & 1, kx = t % 3;   // compile-time per unrolled t
        const char* p = baseA + ((size_t)(ky * 8 + ich * 4) * XPAD + kx) * 16 + voffA;
#pragma unroll
        for (int mf = 0; mf < 4; ++mf)
            af[mf] = *(const bf16x8*)(p + mf * 256);
    };
    auto loadB = [&](bf16x8* bf, int t) {
        const int s6 = t / 3, kx = t % 3;
        const int sB = ((s6 >> 1) * 3 + kx) * 2 + (s6 & 1);
        const char* p = bt + (size_t)sB * 8192 + voffB;
#pragma unroll
        for (int nf = 0; nf < 4; ++nf)
            bf[nf] = *(const bf16x8*)(p + nf * 256);
    };
    auto domfma = [&](const bf16x8* af, const bf16x8* bf) {
        __builtin_amdgcn_s_setprio(1);
#pragma unroll
        for (int mf = 0; mf < 4; ++mf)
#pragma unroll
            for (int nf = 0; nf < 4; ++nf)
                acc[mf][nf] = __builtin_amdgcn_mfma_f32_16x16x32_bf16(
                    af[mf], bf[nf], acc[mf][nf], 0, 0, 0);
        __builtin_amdgcn_s_setprio(0);
    };

    bf16x8 aA[4], bA[4], aB[4], bB[4];
    loadA(aA, 0); loadB(bA, 0);

#pragma unroll
    for (int tt = 0; tt < 9; ++tt) {
        const int t0 = 2 * tt;
        loadA(aB, t0 + 1); loadB(bB, t0 + 1);   // prefetch t0+1
        domfma(aA, bA);                          // compiler waits vmcnt(8)
        if (t0 + 2 < 18) { loadA(aA, t0 + 2); loadB(bA, t0 + 2); }
        domfma(aB, bB);
    }

    int b = b0 + bl;
#pragma unroll
    for (int mf = 0; mf < 4; ++mf) {
        int ox0 = x0 + wm * 64 + mf * 16 + (lc << 2);
#pragma unroll
        for (int nf = 0; nf < 4; ++nf) {
            int oc = wn * 64 + nf * 16 + lr;
            float* po = out + (((size_t)b * OC + oc) * OH2 + oy) * OH2 + ox0;
            if (ox0 + 3 < OH2) {
                *(f32x4u*)po = acc[mf][nf];
            } else {
#pragma unroll
                for (int rr = 0; rr < 4; ++rr)
                    if (ox0 + rr < OH2) po[rr] = acc[mf][nf][rr];
            }
        }
    }
}

// ---------------------------------------------------------------------------
extern "C" void kernel_launch(void* const* d_in, const int* in_sizes, int n_in,
                              void* d_out, int out_size, void* d_ws, size_t ws_size,
                              hipStream_t stream) {
    const float* x      = (const float*)d_in[0];
    const float* w_p    = (const float*)d_in[1];
    const float* b_p    = (const float*)d_in[2];
    const float* w_conv = (const float*)d_in[3];
    float* out = (float*)d_out;

    const size_t offElems = (size_t)B_ * 18 * HH * WW;          // f32
    const size_t xtElems  = (size_t)B_ * HH * WW * IC;          // bf16 NHWC copy
    const size_t btElems  = (size_t)18 * 4 * 128 * 8;           // bf16
    const size_t xofElems = (size_t)XOF * 8 * XPAD * 8;         // bf16 per batch
    const size_t slack    = 16384;

    float* off = (float*)d_ws;
    unsigned short* xtb  = (unsigned short*)(off + offElems);
    unsigned short* Bt   = xtb + xtElems;
    unsigned short* xoff = Bt + btElems;

    const size_t headBytes = offElems * 4 + (xtElems + btElems) * 2;
    const bool allBatch = ws_size >= headBytes + 4 * xofElems * 2 + slack;

    prologue<<<3360, 256, 0, stream>>>(x, w_p, b_p, w_conv, off, xtb, Bt);

    if (allBatch) {
        int snwg = 12 * XOF * B_;                 // 18432
        sample_nhwc<<<snwg, 256, 0, stream>>>(xtb, off, xoff, 0, snwg);
        int cnwg = 3 * OH2 * B_;                  // 4584
        conv2_mfma<<<cnwg, 256, 0, stream>>>(xoff, Bt, out, 0, cnwg);
    } else {
        for (int b = 0; b < B_; ++b) {
            int snwg = 12 * XOF;                  // 4608
            sample_nhwc<<<snwg, 256, 0, stream>>>(xtb, off, xoff, b, snwg);
            int cnwg = 3 * OH2;                   // 1146
            conv2_mfma<<<cnwg, 256, 0, stream>>>(xoff, Bt, out, b, cnwg);
        }
    }
}

// Round 16
// 217.651 us; speedup vs baseline: 1.0794x; 1.0794x over previous
//
#include <hip/hip_runtime.h>
#include <hip/hip_bf16.h>

#define B_   4
#define IC   64
#define OC   128
#define HH   128
#define WW   128
#define HP   130      // padded H/W for sampling
#define XOF  384      // x_off spatial (128*3)
#define XPAD 388      // padded x-dim of granule layout
#define OH2  382      // final output spatial

typedef __attribute__((ext_vector_type(4))) float f32x4;
typedef __attribute__((ext_vector_type(8))) __bf16 bf16x8;
typedef __attribute__((ext_vector_type(8))) unsigned short us8;
typedef __attribute__((ext_vector_type(4), aligned(4))) float f32x4u;

__device__ __forceinline__ void gload16(const void* gsrc, void* ldst) {
    __builtin_amdgcn_global_load_lds(
        (const __attribute__((address_space(1))) void*)gsrc,
        (__attribute__((address_space(3))) void*)ldst, 16, 0, 0);
}

#define WAITV(N) asm volatile("s_waitcnt vmcnt(" #N ")" ::: "memory")

__device__ __forceinline__ float bf2f(unsigned short u) {
    union { unsigned int i; float f; } v; v.i = ((unsigned int)u) << 16; return v.f;
}
__device__ __forceinline__ unsigned short f2bf(float f) {
    __hip_bfloat16 h = __float2bfloat16(f);
    return reinterpret_cast<unsigned short&>(h);
}

// ---------------------------------------------------------------------------
// FUSED PROLOGUE (byte-identical to R14): transpose-to-bf16-NHWC / offset
// conv / prep_w in one dispatch.
// ---------------------------------------------------------------------------
__global__ __launch_bounds__(256) void prologue(const float* __restrict__ x,
                                                const float* __restrict__ w_p,
                                                const float* __restrict__ b_p,
                                                const float* __restrict__ wc,
                                                float* __restrict__ off,
                                                unsigned short* __restrict__ xt,
                                                unsigned short* __restrict__ Bt) {
    __shared__ __align__(16) char smem[18432];
    int bid = blockIdx.x;
    int tid = threadIdx.x;

    if (bid < 2048) {
        // ---- transpose to bf16 NHWC ----
        unsigned short (*tile)[34] = (unsigned short(*)[34])smem;  // 64x34 ushort
        int xt4 = bid & 3;
        int y   = (bid >> 2) & 127;
        int b   = bid >> 9;
        int x0  = xt4 * 32;

        int xl = tid & 31;
        int c8 = tid >> 5;
#pragma unroll
        for (int it = 0; it < 8; ++it) {
            int c = it * 8 + c8;
            tile[c][xl] = f2bf(x[(((size_t)b * IC + c) * HH + y) * WW + x0 + xl]);
        }
        __syncthreads();
        int c2 = (tid & 31) * 2;
#pragma unroll
        for (int it = 0; it < 4; ++it) {
            int xx = (tid >> 5) + it * 8;
            ushort2 v = { tile[c2][xx], tile[c2 + 1][xx] };
            *(ushort2*)(xt + (((size_t)b * HH + y) * WW + x0 + xx) * IC + c2) = v;
        }
    } else if (bid < 3072) {
        // ---- offset conv ----
        float (*part)[64][18] = (float(*)[64][18])smem;   // 4x64x18 f32
        int obid = bid - 2048;
        int pxl = tid & 63;
        int icq = tid >> 6;
        int seg = obid & 1;
        int row = obid >> 1;
        int py  = row & 127;
        int b   = row >> 7;
        int px  = seg * 64 + pxl;
        int ic0 = __builtin_amdgcn_readfirstlane(icq << 4);

        float acc[18];
#pragma unroll
        for (int co = 0; co < 18; ++co) acc[co] = 0.f;

        const float* xb = x + ((size_t)b * IC + ic0) * HH * WW;

        for (int ci = 0; ci < 16; ++ci) {
            const float* xc = xb + (size_t)ci * HH * WW;
            float xv[9];
#pragma unroll
            for (int ky = 0; ky < 3; ++ky) {
                int yy = py + ky - 1;
                bool yok = (yy >= 0) && (yy < HH);
#pragma unroll
                for (int kx = 0; kx < 3; ++kx) {
                    int xx = px + kx - 1;
                    bool ok = yok && (xx >= 0) && (xx < WW);
                    xv[ky * 3 + kx] = ok ? xc[yy * WW + xx] : 0.f;
                }
            }
#pragma unroll
            for (int co = 0; co < 18; ++co) {
                const float* wrow = w_p + ((size_t)co * IC + ic0 + ci) * 9;
                f32x4u w0 = *(const f32x4u*)wrow;
                f32x4u w1 = *(const f32x4u*)(wrow + 4);
                float  w8 = wrow[8];
                acc[co] = fmaf(w0.x, xv[0], acc[co]);
                acc[co] = fmaf(w0.y, xv[1], acc[co]);
                acc[co] = fmaf(w0.z, xv[2], acc[co]);
                acc[co] = fmaf(w0.w, xv[3], acc[co]);
                acc[co] = fmaf(w1.x, xv[4], acc[co]);
                acc[co] = fmaf(w1.y, xv[5], acc[co]);
                acc[co] = fmaf(w1.z, xv[6], acc[co]);
                acc[co] = fmaf(w1.w, xv[7], acc[co]);
                acc[co] = fmaf(w8,   xv[8], acc[co]);
            }
        }

#pragma unroll
        for (int co = 0; co < 18; ++co) part[icq][pxl][co] = acc[co];
        __syncthreads();

        for (int co = icq; co < 18; co += 4) {
            float s = b_p[co] + part[0][pxl][co] + part[1][pxl][co]
                              + part[2][pxl][co] + part[3][pxl][co];
            off[((size_t)b * 18 + co) * HH * WW + (size_t)py * WW + px] = s;
        }
    } else {
        // ---- prep_w ----
        int t = (bid - 3072) * 256 + tid;
        if (t < 18 * 4 * 128 * 8) {
            int e  = t & 7;
            int oc = (t >> 3) & 127;
            int kg = (t >> 10) & 3;
            int s  = t >> 12;
            int ic = ((s & 1) << 5) + (kg << 3) + e;
            int kpos = s >> 1;
            int ky = kpos / 3, kx = kpos % 3;
            Bt[t] = f2bf(wc[(((size_t)oc * IC + ic) * 3 + ky) * 3 + kx]);
        }
    }
}

// ---------------------------------------------------------------------------
// Kernel B v4 (byte-identical to R14): bilinear sampling from bf16 NHWC xt.
// ---------------------------------------------------------------------------
__global__ __launch_bounds__(256) void sample_nhwc(const unsigned short* __restrict__ xt,
                                                   const float* __restrict__ off,
                                                   unsigned short* __restrict__ xoff,
                                                   int b0, int nwg) {
    int orig = blockIdx.x;
    int chunk = nwg >> 3;
    int wg = (orig & 7) * chunk + (orig >> 3);

    int xtile = wg % 12;
    int tmp = wg / 12;
    int yy  = tmp % XOF;
    int bl  = tmp / XOF;
    int b   = b0 + bl;
    int xx0 = xtile * 32;

    int t  = threadIdx.x;
    int xl = t & 31;
    int cg = t >> 5;
    int xx = xx0 + xl;

    int j = xx / 3, kw = xx % 3;
    int i = yy / 3, kh = yy % 3;
    int n = kh * 3 + kw;

    const float* offb = off + (size_t)b * 18 * HH * WW + (size_t)i * WW + j;
    float offr = offb[(size_t)n * HH * WW];
    float offc = offb[(size_t)(n + 9) * HH * WW];

    float pr = (float)(i + kh) + offr;
    float pc = (float)(j + kw) + offc;

    float r0f = floorf(pr), c0f = floorf(pc);
    int r0 = min(max((int)r0f, 0), HP - 1);
    int c0 = min(max((int)c0f, 0), HP - 1);
    int r1 = min(max((int)(r0f + 1.f), 0), HP - 1);
    int c1 = min(max((int)(c0f + 1.f), 0), HP - 1);

    float prc = fminf(fmaxf(pr, 0.f), (float)(HP - 1));
    float pcc = fminf(fmaxf(pc, 0.f), (float)(HP - 1));

    float R0 = 1.f + ((float)r0 - prc);
    float R1 = 1.f - ((float)r1 - prc);
    float C0 = 1.f + ((float)c0 - pcc);
    float C1 = 1.f - ((float)c1 - pcc);

    int rr0 = r0 - 1, cc0 = c0 - 1, rr1 = r1 - 1, cc1 = c1 - 1;
    if (!(rr0 >= 0 && rr0 < HH)) R0 = 0.f;
    if (!(rr1 >= 0 && rr1 < HH)) R1 = 0.f;
    float C0m = (cc0 >= 0 && cc0 < WW) ? C0 : 0.f;
    float C1m = (cc1 >= 0 && cc1 < WW) ? C1 : 0.f;
    int ra0 = min(max(rr0, 0), HH - 1);
    int ra1 = min(max(rr1, 0), HH - 1);
    int ca0 = min(max(cc0, 0), WW - 1);
    int ca1 = min(max(cc1, 0), WW - 1);

    const unsigned short* xb = xt + (size_t)b * HH * WW * IC + cg * 8;
    us8 a  = *(const us8*)(xb + ((size_t)ra0 * WW + ca0) * IC);
    us8 bb = *(const us8*)(xb + ((size_t)ra0 * WW + ca1) * IC);
    us8 cc = *(const us8*)(xb + ((size_t)ra1 * WW + ca0) * IC);
    us8 dd = *(const us8*)(xb + ((size_t)ra1 * WW + ca1) * IC);

    us8 res;
#pragma unroll
    for (int e = 0; e < 8; ++e) {
        float v = R0 * (C0m * bf2f(a[e]) + C1m * bf2f(bb[e])) +
                  R1 * (C0m * bf2f(cc[e]) + C1m * bf2f(dd[e]));
        res[e] = f2bf(v);
    }

    size_t di = ((((size_t)bl * XOF + yy) * 8 + cg) * XPAD + xx) * 8;
    *(us8*)(xoff + di) = res;
}

// ---------------------------------------------------------------------------
// Kernel C v10: v8 structure with a DEEPER pipeline where it was short.
// B triple-buffered (3x8KB), staged 2 K-steps ahead (~640cy lead > L3 lat);
// A full-slab staged at kx==0 (2-3 step lead). All stages issued AFTER the
// barrier -> the second barrier is provably unnecessary (buffer reuse gap
// >= 1 full barrier interval) -> 18 barriers/block instead of 36. Counted
// vmcnt table derived by queue simulation:
//   N(t) = 0 @t=17 ; 5 @t in {1,4,7,10,13} ; else 2
// (waits exactly tile-t's loads; keeps t+1 / t+2 loads in flight).
// LDS 48KB -> 3 blocks/CU; regs ~= v8 (64 VGPR + 64 AGPR).
// ---------------------------------------------------------------------------
__global__ __launch_bounds__(256) void conv2_mfma(const unsigned short* __restrict__ xoff,
                                                  const unsigned short* __restrict__ Bt,
                                                  float* __restrict__ out,
                                                  int b0, int nwg) {
    __shared__ __align__(16) char lds[49152];
    // A dbuf:   [abuf:2][cg:4][px:192][16B] at abuf*12288  (24KB)
    // B tribuf: [buf:3][kg:4][oc:128][16B]  at 24576+buf*8192 (24KB)

    // bijective XCD-chunk swizzle (m204)
    int orig = blockIdx.x;
    int q = nwg >> 3, r = nwg & 7;
    int xcd = orig & 7, loc = orig >> 3;
    int wgid = (xcd < r ? xcd * (q + 1) : r * (q + 1) + (xcd - r) * q) + loc;

    int xt  = wgid % 3;
    int tmp = wgid / 3;
    int oy  = tmp % OH2;
    int bl  = tmp / OH2;
    int x0  = xt << 7;

    int tid  = threadIdx.x;
    int wave = tid >> 6, lane = tid & 63;
    int wm = wave >> 1;            // px half
    int wn = wave & 1;             // oc half
    int lr = lane & 15, lc = lane >> 4;

    const char* xb = (const char*)xoff + (size_t)bl * ((size_t)XOF * 8 * XPAD * 16);
    const char* bt = (const char*)Bt;

    f32x4 acc[4][4];
#pragma unroll
    for (int mf = 0; mf < 4; ++mf)
#pragma unroll
        for (int nf = 0; nf < 4; ++nf)
            acc[mf][nf] = (f32x4){0.f, 0.f, 0.f, 0.f};

    // full A slab for super-step s6 into abuf: 3 gloads per wave.
    auto stageA_full = [&](int abuf, int s6) {
#pragma unroll
        for (int qq = 0; qq < 3; ++qq) {
            int ky  = s6 >> 1;
            int ich = s6 & 1;
            int L   = wave * 3 + qq;
            int cg  = L / 3, seg = L % 3;
            const char* src = xb +
                (((size_t)(oy + ky) * 8 + ich * 4 + cg) * XPAD + x0 + seg * 64 + lane) * 16;
            char* dst = lds + abuf * 12288 + (cg * 192 + seg * 64) * 16;
            gload16(src, dst);
        }
    };
    // B tile for K-step t into tri-buffer t%3: 2 gloads per wave.
    auto stageB = [&](int t) {
        int s6 = t / 3, kx = t % 3;
        int sB = ((s6 >> 1) * 3 + kx) * 2 + (s6 & 1);
        int buf = t % 3;
        const char* bsrc = bt + (size_t)sB * 8192;
#pragma unroll
        for (int g2 = 0; g2 < 2; ++g2) {
            int g = wave * 2 + g2;
            gload16(bsrc + (size_t)g * 1024 + lane * 16,
                    lds + 24576 + buf * 8192 + g * 1024);
        }
    };

    auto compute = [&](int abuf, int t, int kx) {
        const char* abase = lds + abuf * 12288;
        const char* bbase = lds + 24576 + (t % 3) * 8192;
        bf16x8 af[4], bfr[4];
#pragma unroll
        for (int mf = 0; mf < 4; ++mf)
            af[mf] = *(const bf16x8*)(abase +
                (lc * 192 + wm * 64 + mf * 16 + lr + kx) * 16);
#pragma unroll
        for (int nf = 0; nf < 4; ++nf)
            bfr[nf] = *(const bf16x8*)(bbase +
                (lc * 128 + wn * 64 + nf * 16 + lr) * 16);
        __builtin_amdgcn_s_setprio(1);
#pragma unroll
        for (int mf = 0; mf < 4; ++mf)
#pragma unroll
            for (int nf = 0; nf < 4; ++nf)
                acc[mf][nf] = __builtin_amdgcn_mfma_f32_16x16x32_bf16(
                    af[mf], bfr[nf], acc[mf][nf], 0, 0, 0);
        __builtin_amdgcn_s_setprio(0);
    };

    // prologue: A(0) x3 + B(0) x2 + B(1) x2 = 7 loads/wave in flight
    stageA_full(0, 0);
    stageB(0);
    stageB(1);

#pragma unroll
    for (int t = 0; t < 18; ++t) {
        const int kx = t % 3, s6 = t / 3;
        // counted wait (queue-simulated): forces tile-t loads, keeps newer flying
        const int n = (t == 17) ? 0 : ((t % 3 == 1 && t < 15) ? 5 : 2);
        if (n == 0)      { WAITV(0); }
        else if (n == 2) { WAITV(2); }
        else             { WAITV(5); }
        __builtin_amdgcn_s_barrier();
        __builtin_amdgcn_sched_barrier(0);
        // stages AFTER barrier: write targets were last read >=1 barrier ago
        if (t + 2 < 18) stageB(t + 2);
        if (kx == 0 && s6 + 1 < 6) stageA_full((s6 & 1) ^ 1, s6 + 1);
        compute(s6 & 1, t, kx);
        __builtin_amdgcn_sched_barrier(0);
    }

    int b = b0 + bl;
#pragma unroll
    for (int mf = 0; mf < 4; ++mf) {
        int ox0 = x0 + wm * 64 + mf * 16 + (lc << 2);
#pragma unroll
        for (int nf = 0; nf < 4; ++nf) {
            int oc = wn * 64 + nf * 16 + lr;
            float* po = out + (((size_t)b * OC + oc) * OH2 + oy) * OH2 + ox0;
            if (ox0 + 3 < OH2) {
                *(f32x4u*)po = acc[mf][nf];
            } else {
#pragma unroll
                for (int rr = 0; rr < 4; ++rr)
                    if (ox0 + rr < OH2) po[rr] = acc[mf][nf][rr];
            }
        }
    }
}

// ---------------------------------------------------------------------------
extern "C" void kernel_launch(void* const* d_in, const int* in_sizes, int n_in,
                              void* d_out, int out_size, void* d_ws, size_t ws_size,
                              hipStream_t stream) {
    const float* x      = (const float*)d_in[0];
    const float* w_p    = (const float*)d_in[1];
    const float* b_p    = (const float*)d_in[2];
    const float* w_conv = (const float*)d_in[3];
    float* out = (float*)d_out;

    const size_t offElems = (size_t)B_ * 18 * HH * WW;          // f32
    const size_t xtElems  = (size_t)B_ * HH * WW * IC;          // bf16 NHWC copy
    const size_t btElems  = (size_t)18 * 4 * 128 * 8;           // bf16
    const size_t xofElems = (size_t)XOF * 8 * XPAD * 8;         // bf16 per batch
    const size_t slack    = 16384;

    float* off = (float*)d_ws;
    unsigned short* xtb  = (unsigned short*)(off + offElems);
    unsigned short* Bt   = xtb + xtElems;
    unsigned short* xoff = Bt + btElems;

    const size_t headBytes = offElems * 4 + (xtElems + btElems) * 2;
    const bool allBatch = ws_size >= headBytes + 4 * xofElems * 2 + slack;

    prologue<<<3360, 256, 0, stream>>>(x, w_p, b_p, w_conv, off, xtb, Bt);

    if (allBatch) {
        int snwg = 12 * XOF * B_;                 // 18432
        sample_nhwc<<<snwg, 256, 0, stream>>>(xtb, off, xoff, 0, snwg);
        int cnwg = 3 * OH2 * B_;                  // 4584
        conv2_mfma<<<cnwg, 256, 0, stream>>>(xoff, Bt, out, 0, cnwg);
    } else {
        for (int b = 0; b < B_; ++b) {
            int snwg = 12 * XOF;                  // 4608
            sample_nhwc<<<snwg, 256, 0, stream>>>(xtb, off, xoff, b, snwg);
            int cnwg = 3 * OH2;                   // 1146
            conv2_mfma<<<cnwg, 256, 0, stream>>>(xoff, Bt, out, b, cnwg);
        }
    }
}